// Round 1
// baseline (450.184 us; speedup 1.0000x reference)
//
#include <hip/hip_runtime.h>
#include <math.h>

#define BZ 16
#define SEQ 64
#define CID 207
#define DIN 64
#define OCN 128
#define NN (BZ*CID)        // 3312
#define NE (NN*16)         // 52992
#define ICD (CID*DIN)      // 13248
#define KW 3

// ---------------- mean over seqlen ----------------
__global__ __launch_bounds__(256) void mean_kernel(const float* __restrict__ x,
                                                   float* __restrict__ meanx) {
    int idx = blockIdx.x * 256 + threadIdx.x;
    if (idx >= NN * DIN) return;
    int n = idx >> 6;
    int d = idx & 63;
    int b = n / CID, c = n - b * CID;
    const float* px = x + (size_t)b * SEQ * ICD + (size_t)c * DIN + d;
    float s = 0.f;
    #pragma unroll
    for (int t = 0; t < SEQ; ++t) s += px[(size_t)t * ICD];
    meanx[idx] = s * (1.0f / SEQ);
}

// ---------------- q/k projection (8 nodes per block, 128 threads) ----------------
__global__ __launch_bounds__(128) void qk_kernel(const float* __restrict__ meanx,
                                                 const float* __restrict__ Wq,
                                                 const float* __restrict__ bq,
                                                 const float* __restrict__ Wk,
                                                 const float* __restrict__ bk,
                                                 float* __restrict__ q,
                                                 float* __restrict__ k) {
    __shared__ float ms[8][DIN];
    int n0 = blockIdx.x * 8;
    int tid = threadIdx.x;
    for (int i = tid; i < 8 * DIN; i += 128) {
        int nn = n0 + (i >> 6);
        ms[i >> 6][i & 63] = (nn < NN) ? meanx[(size_t)nn * DIN + (i & 63)] : 0.f;
    }
    __syncthreads();
    int j = tid;
    float accq[8], acck[8];
    float bqv = bq[j], bkv = bk[j];
    #pragma unroll
    for (int r = 0; r < 8; ++r) { accq[r] = bqv; acck[r] = bkv; }
    for (int d = 0; d < DIN; ++d) {
        float wq = Wq[d * OCN + j], wk = Wk[d * OCN + j];
        #pragma unroll
        for (int r = 0; r < 8; ++r) {
            float mv = ms[r][d];
            accq[r] += mv * wq;
            acck[r] += mv * wk;
        }
    }
    const float qscale = 0.088388347648318447f;  // 1/sqrt(128)
    #pragma unroll
    for (int r = 0; r < 8; ++r) {
        int nn = n0 + r;
        if (nn < NN) {
            q[(size_t)nn * OCN + j] = accq[r] * qscale;
            k[(size_t)nn * OCN + j] = acck[r];
        }
    }
}

// ---------------- CSR build ----------------
__global__ __launch_bounds__(256) void hist_kernel(const int* __restrict__ dst,
                                                   int* __restrict__ cnt) {
    int e = blockIdx.x * 256 + threadIdx.x;
    if (e < NE) atomicAdd(&cnt[dst[e]], 1);
}

__global__ __launch_bounds__(1024) void scan_kernel(const int* __restrict__ cnt,
                                                    int* __restrict__ offs) {
    __shared__ int sums[1024], sums2[1024];
    int tid = threadIdx.x;
    int base = tid * 4;
    int v[4];
    #pragma unroll
    for (int i = 0; i < 4; ++i) v[i] = (base + i < NN) ? cnt[base + i] : 0;
    sums[tid] = v[0] + v[1] + v[2] + v[3];
    __syncthreads();
    int* a = sums;
    int* b2 = sums2;
    for (int off = 1; off < 1024; off <<= 1) {
        int val = a[tid] + ((tid >= off) ? a[tid - off] : 0);
        b2[tid] = val;
        __syncthreads();
        int* t = a; a = b2; b2 = t;
    }
    int prev = (tid > 0) ? a[tid - 1] : 0;
    int run = prev;
    #pragma unroll
    for (int i = 0; i < 4; ++i) {
        if (base + i <= NN) offs[base + i] = run;
        run += v[i];
    }
}

__global__ __launch_bounds__(256) void scatter_kernel(const int* __restrict__ src,
                                                      const int* __restrict__ dst,
                                                      const int* __restrict__ offs,
                                                      int* __restrict__ fill,
                                                      int* __restrict__ csr_src) {
    int e = blockIdx.x * 256 + threadIdx.x;
    if (e >= NE) return;
    int d0 = dst[e];
    int pos = offs[d0] + atomicAdd(&fill[d0], 1);
    csr_src[pos] = src[e];
}

// ---------------- fused scores + softmax + weighted gather (writes y[b][t][ic]) ----------------
__global__ __launch_bounds__(256) void gather_kernel(const float* __restrict__ x,
                                                     const float* __restrict__ q,
                                                     const float* __restrict__ k,
                                                     const int* __restrict__ offs,
                                                     const int* __restrict__ csr,
                                                     float* __restrict__ y) {
    __shared__ float qs[OCN];
    __shared__ float sc[1024];
    __shared__ int sidx[1024];
    int n = blockIdx.x;
    int b = n / CID, c = n - b * CID;
    int start = offs[n];
    int deg = offs[n + 1] - start;
    if (deg > 1024) deg = 1024;  // cannot happen with this data (max ~45)
    int tid = threadIdx.x;
    if (tid < OCN) qs[tid] = q[(size_t)n * OCN + tid];
    for (int i = tid; i < deg; i += 256) sidx[i] = csr[start + i];
    __syncthreads();
    int lane = tid & 63;
    int wv = tid >> 6;
    for (int i = wv; i < deg; i += 4) {
        const float* kk = k + (size_t)sidx[i] * OCN;
        float p = kk[lane] * qs[lane] + kk[lane + 64] * qs[lane + 64];
        #pragma unroll
        for (int off = 32; off; off >>= 1) p += __shfl_down(p, off);
        if (lane == 0) sc[i] = p;
    }
    __syncthreads();
    float m = -1e30f;
    for (int i = 0; i < deg; ++i) m = fmaxf(m, sc[i]);
    __syncthreads();
    for (int i = tid; i < deg; i += 256) sc[i] = __expf(sc[i] - m);
    __syncthreads();
    float ssum = 0.f;
    for (int i = 0; i < deg; ++i) ssum += sc[i];
    float inv = (deg > 0) ? (1.0f / ssum) : 0.f;

    int dg = tid & 15;   // d block: d = dg*4 .. dg*4+3
    int t0 = tid >> 4;   // t = t0 + 16*kk
    float4 a0 = make_float4(0.f, 0.f, 0.f, 0.f);
    float4 a1 = a0, a2 = a0, a3 = a0;
    for (int i = 0; i < deg; ++i) {
        float al = sc[i] * inv;
        int s = sidx[i];
        int sb = s / CID, scn = s - sb * CID;
        const float* vx = x + (size_t)sb * SEQ * ICD + (size_t)scn * DIN + (dg << 2);
        float4 v0 = *(const float4*)(vx + (size_t)(t0) * ICD);
        float4 v1 = *(const float4*)(vx + (size_t)(t0 + 16) * ICD);
        float4 v2 = *(const float4*)(vx + (size_t)(t0 + 32) * ICD);
        float4 v3 = *(const float4*)(vx + (size_t)(t0 + 48) * ICD);
        a0.x += al * v0.x; a0.y += al * v0.y; a0.z += al * v0.z; a0.w += al * v0.w;
        a1.x += al * v1.x; a1.y += al * v1.y; a1.z += al * v1.z; a1.w += al * v1.w;
        a2.x += al * v2.x; a2.y += al * v2.y; a2.z += al * v2.z; a2.w += al * v2.w;
        a3.x += al * v3.x; a3.y += al * v3.y; a3.z += al * v3.z; a3.w += al * v3.w;
    }
    float* py = y + (size_t)b * SEQ * ICD + (size_t)c * DIN + (dg << 2);
    *(float4*)(py + (size_t)(t0) * ICD) = a0;
    *(float4*)(py + (size_t)(t0 + 16) * ICD) = a1;
    *(float4*)(py + (size_t)(t0 + 32) * ICD) = a2;
    *(float4*)(py + (size_t)(t0 + 48) * ICD) = a3;
}

// ---------------- conv1d (K=3, SAME) as K-split tiled GEMM ----------------
#define ICCHUNK 24
__global__ __launch_bounds__(256) void conv_kernel(const float* __restrict__ y,
                                                   const float* __restrict__ cw,
                                                   float* __restrict__ out) {
    __shared__ float ys[ICCHUNK][SEQ + 2];
    __shared__ float ws[ICCHUNK][KW][64];
    int bid = blockIdx.x;
    int b = bid >> 4;
    int oh = (bid >> 3) & 1;
    int ks = bid & 7;
    const int icPer = ICD / 8;  // 1656, divisible by ICCHUNK=24
    int tid = threadIdx.x;
    int tt = tid & 15;
    int ob = tid >> 4;
    float acc[4][4];
    #pragma unroll
    for (int i = 0; i < 4; ++i)
        #pragma unroll
        for (int j = 0; j < 4; ++j) acc[i][j] = 0.f;

    int trow = tid >> 2;
    int il0 = (tid & 3) * 6;
    int oc_l = tid >> 2;
    int part = tid & 3;

    for (int icc = 0; icc < icPer; icc += ICCHUNK) {
        int icbase = ks * icPer + icc;
        {
            const float* src = y + (size_t)b * SEQ * ICD + (size_t)trow * ICD + icbase + il0;
            #pragma unroll
            for (int u = 0; u < 6; ++u) ys[il0 + u][trow + 1] = src[u];
        }
        if (tid < ICCHUNK * 2) {
            int il = tid >> 1;
            ys[il][(tid & 1) ? (SEQ + 1) : 0] = 0.f;
        }
        {
            const float* src = cw + (size_t)(oh * 64 + oc_l) * (ICD * KW) + (size_t)icbase * KW + part * 18;
            #pragma unroll
            for (int u = 0; u < 18; ++u) {
                int idx = part * 18 + u;
                int il = idx / 3, w = idx - il * 3;
                ws[il][w][oc_l] = src[u];
            }
        }
        __syncthreads();
        #pragma unroll 4
        for (int il = 0; il < ICCHUNK; ++il) {
            #pragma unroll
            for (int w = 0; w < KW; ++w) {
                float a0 = ys[il][tt + w];
                float a1 = ys[il][tt + 16 + w];
                float a2 = ys[il][tt + 32 + w];
                float a3 = ys[il][tt + 48 + w];
                float4 bv = *(const float4*)&ws[il][w][ob << 2];
                acc[0][0] += a0 * bv.x; acc[0][1] += a0 * bv.y; acc[0][2] += a0 * bv.z; acc[0][3] += a0 * bv.w;
                acc[1][0] += a1 * bv.x; acc[1][1] += a1 * bv.y; acc[1][2] += a1 * bv.z; acc[1][3] += a1 * bv.w;
                acc[2][0] += a2 * bv.x; acc[2][1] += a2 * bv.y; acc[2][2] += a2 * bv.z; acc[2][3] += a2 * bv.w;
                acc[3][0] += a3 * bv.x; acc[3][1] += a3 * bv.y; acc[3][2] += a3 * bv.z; acc[3][3] += a3 * bv.w;
            }
        }
        __syncthreads();
    }
    float* po = out + (size_t)b * SEQ * OCN + oh * 64 + (ob << 2);
    #pragma unroll
    for (int ti = 0; ti < 4; ++ti) {
        int t = tt + 16 * ti;
        float* pt = po + (size_t)t * OCN;
        atomicAdd(pt + 0, acc[ti][0]);
        atomicAdd(pt + 1, acc[ti][1]);
        atomicAdd(pt + 2, acc[ti][2]);
        atomicAdd(pt + 3, acc[ti][3]);
    }
}

extern "C" void kernel_launch(void* const* d_in, const int* in_sizes, int n_in,
                              void* d_out, int out_size, void* d_ws, size_t ws_size,
                              hipStream_t stream) {
    const float* x   = (const float*)d_in[0];
    const float* Wq  = (const float*)d_in[1];
    const float* bqv = (const float*)d_in[2];
    const float* Wk  = (const float*)d_in[3];
    const float* bkv = (const float*)d_in[4];
    const float* cw  = (const float*)d_in[5];
    const int* esrc  = (const int*)d_in[6];
    const int* edst  = (const int*)d_in[7];

    char* ws = (char*)d_ws;
    size_t o = 0;
    auto alloc = [&](size_t bytes) {
        void* p = ws + o;
        o += (bytes + 255) & ~(size_t)255;
        return p;
    };
    float* meanx = (float*)alloc((size_t)NN * DIN * 4);
    float* q     = (float*)alloc((size_t)NN * OCN * 4);
    float* k     = (float*)alloc((size_t)NN * OCN * 4);
    int*   cnt   = (int*)alloc(4096 * 4);
    int*   fill  = (int*)alloc(4096 * 4);
    int*   offs  = (int*)alloc(4352 * 4);
    int*   csr   = (int*)alloc((size_t)NE * 4);
    float* y     = (float*)alloc((size_t)BZ * SEQ * ICD * 4);

    hipMemsetAsync(cnt, 0, 4096 * 4, stream);
    hipMemsetAsync(fill, 0, 4096 * 4, stream);
    hipMemsetAsync(d_out, 0, (size_t)out_size * 4, stream);

    mean_kernel<<<dim3((NN * DIN + 255) / 256), dim3(256), 0, stream>>>(x, meanx);
    qk_kernel<<<dim3(NN / 8), dim3(128), 0, stream>>>(meanx, Wq, bqv, Wk, bkv, q, k);
    hist_kernel<<<dim3((NE + 255) / 256), dim3(256), 0, stream>>>(edst, cnt);
    scan_kernel<<<dim3(1), dim3(1024), 0, stream>>>(cnt, offs);
    scatter_kernel<<<dim3((NE + 255) / 256), dim3(256), 0, stream>>>(esrc, edst, offs, fill, csr);
    gather_kernel<<<dim3(NN), dim3(256), 0, stream>>>(x, q, k, offs, csr, y);
    conv_kernel<<<dim3(256), dim3(256), 0, stream>>>(y, cw, (float*)d_out);
}

// Round 2
// 221.210 us; speedup vs baseline: 2.0351x; 2.0351x over previous
//
#include <hip/hip_runtime.h>
#include <hip/hip_bf16.h>
#include <math.h>

#define BZ 16
#define SEQ 64
#define CID 207
#define DIN 64
#define OCN 128
#define NN (BZ*CID)        // 3312
#define NE (NN*16)         // 52992
#define ICD (CID*DIN)      // 13248
#define KW 3
#define NKSTEP 414         // ICD/32
#define NKPAD 416          // padded to 32*13
#define NKC 32             // K-split chunks
#define KSPC 13            // ksteps per chunk
#define XTOT ((size_t)BZ*SEQ*ICD)   // 13565952

typedef __attribute__((ext_vector_type(8))) short bf16x8;
typedef __attribute__((ext_vector_type(4))) float f32x4;
typedef unsigned short u16;
typedef unsigned int u32;

__device__ __forceinline__ float bflo(u32 u) {
    u32 v = u << 16;
    return __builtin_bit_cast(float, v);
}
__device__ __forceinline__ float bfhi(u32 u) {
    u32 v = u & 0xFFFF0000u;
    return __builtin_bit_cast(float, v);
}
__device__ __forceinline__ u16 f2bf(float f) {
    __hip_bfloat16 h = __float2bfloat16(f);
    return __builtin_bit_cast(u16, h);
}
__device__ __forceinline__ u32 packbf(float f0, float f1) {
    return ((u32)f2bf(f1) << 16) | (u32)f2bf(f0);
}

// ---------------- x fp32 -> bf16 ----------------
__global__ __launch_bounds__(256) void cvt_kernel(const float* __restrict__ x,
                                                  u16* __restrict__ xb) {
    size_t i = ((size_t)blockIdx.x * 256 + threadIdx.x) * 8;
    if (i >= XTOT) return;
    float4 a = *(const float4*)(x + i);
    float4 b = *(const float4*)(x + i + 4);
    uint4 o;
    o.x = packbf(a.x, a.y);
    o.y = packbf(a.z, a.w);
    o.z = packbf(b.x, b.y);
    o.w = packbf(b.z, b.w);
    *(uint4*)(xb + i) = o;
}

// ---------------- mean over seqlen ----------------
__global__ __launch_bounds__(256) void mean_kernel(const float* __restrict__ x,
                                                   float* __restrict__ meanx) {
    int idx = blockIdx.x * 256 + threadIdx.x;
    if (idx >= NN * DIN) return;
    int n = idx >> 6;
    int d = idx & 63;
    int b = n / CID, c = n - b * CID;
    const float* px = x + (size_t)b * SEQ * ICD + (size_t)c * DIN + d;
    float s = 0.f;
    #pragma unroll
    for (int t = 0; t < SEQ; ++t) s += px[(size_t)t * ICD];
    meanx[idx] = s * (1.0f / SEQ);
}

// ---------------- q/k projection ----------------
__global__ __launch_bounds__(128) void qk_kernel(const float* __restrict__ meanx,
                                                 const float* __restrict__ Wq,
                                                 const float* __restrict__ bq,
                                                 const float* __restrict__ Wk,
                                                 const float* __restrict__ bk,
                                                 float* __restrict__ q,
                                                 float* __restrict__ k) {
    __shared__ float ms[8][DIN];
    int n0 = blockIdx.x * 8;
    int tid = threadIdx.x;
    for (int i = tid; i < 8 * DIN; i += 128) {
        int nn = n0 + (i >> 6);
        ms[i >> 6][i & 63] = (nn < NN) ? meanx[(size_t)nn * DIN + (i & 63)] : 0.f;
    }
    __syncthreads();
    int j = tid;
    float accq[8], acck[8];
    float bqv = bq[j], bkv = bk[j];
    #pragma unroll
    for (int r = 0; r < 8; ++r) { accq[r] = bqv; acck[r] = bkv; }
    for (int d = 0; d < DIN; ++d) {
        float wq = Wq[d * OCN + j], wk = Wk[d * OCN + j];
        #pragma unroll
        for (int r = 0; r < 8; ++r) {
            float mv = ms[r][d];
            accq[r] += mv * wq;
            acck[r] += mv * wk;
        }
    }
    const float qscale = 0.088388347648318447f;  // 1/sqrt(128)
    #pragma unroll
    for (int r = 0; r < 8; ++r) {
        int nn = n0 + r;
        if (nn < NN) {
            q[(size_t)nn * OCN + j] = accq[r] * qscale;
            k[(size_t)nn * OCN + j] = acck[r];
        }
    }
}

// ---------------- CSR build ----------------
__global__ __launch_bounds__(256) void hist_kernel(const int* __restrict__ dst,
                                                   int* __restrict__ cnt) {
    int e = blockIdx.x * 256 + threadIdx.x;
    if (e < NE) atomicAdd(&cnt[dst[e]], 1);
}

__global__ __launch_bounds__(1024) void scan_kernel(const int* __restrict__ cnt,
                                                    int* __restrict__ offs) {
    __shared__ int sums[1024], sums2[1024];
    int tid = threadIdx.x;
    int base = tid * 4;
    int v[4];
    #pragma unroll
    for (int i = 0; i < 4; ++i) v[i] = (base + i < NN) ? cnt[base + i] : 0;
    sums[tid] = v[0] + v[1] + v[2] + v[3];
    __syncthreads();
    int* a = sums;
    int* b2 = sums2;
    for (int off = 1; off < 1024; off <<= 1) {
        int val = a[tid] + ((tid >= off) ? a[tid - off] : 0);
        b2[tid] = val;
        __syncthreads();
        int* t = a; a = b2; b2 = t;
    }
    int prev = (tid > 0) ? a[tid - 1] : 0;
    int run = prev;
    #pragma unroll
    for (int i = 0; i < 4; ++i) {
        if (base + i <= NN) offs[base + i] = run;
        run += v[i];
    }
}

__global__ __launch_bounds__(256) void scatter_kernel(const int* __restrict__ src,
                                                      const int* __restrict__ dst,
                                                      const int* __restrict__ offs,
                                                      int* __restrict__ fill,
                                                      int* __restrict__ csr_src) {
    int e = blockIdx.x * 256 + threadIdx.x;
    if (e >= NE) return;
    int d0 = dst[e];
    int pos = offs[d0] + atomicAdd(&fill[d0], 1);
    csr_src[pos] = src[e];
}

// ---------------- fused scores + softmax + weighted gather (bf16 in/out) ----------------
__global__ __launch_bounds__(256) void gather_kernel(const u16* __restrict__ xb,
                                                     const float* __restrict__ q,
                                                     const float* __restrict__ k,
                                                     const int* __restrict__ offs,
                                                     const int* __restrict__ csr,
                                                     u16* __restrict__ yb) {
    __shared__ float qs[OCN];
    __shared__ float sc[1024];
    __shared__ int sidx[1024];
    int n = blockIdx.x;
    int b = n / CID, c = n - b * CID;
    int start = offs[n];
    int deg = offs[n + 1] - start;
    if (deg > 1024) deg = 1024;
    int tid = threadIdx.x;
    if (tid < OCN) qs[tid] = q[(size_t)n * OCN + tid];
    for (int i = tid; i < deg; i += 256) sidx[i] = csr[start + i];
    __syncthreads();
    int lane = tid & 63;
    int wv = tid >> 6;
    for (int i = wv; i < deg; i += 4) {
        const float* kk = k + (size_t)sidx[i] * OCN;
        float p = kk[lane] * qs[lane] + kk[lane + 64] * qs[lane + 64];
        #pragma unroll
        for (int off = 32; off; off >>= 1) p += __shfl_down(p, off);
        if (lane == 0) sc[i] = p;
    }
    __syncthreads();
    float m = -1e30f;
    for (int i = 0; i < deg; ++i) m = fmaxf(m, sc[i]);
    __syncthreads();
    for (int i = tid; i < deg; i += 256) sc[i] = __expf(sc[i] - m);
    __syncthreads();
    float ssum = 0.f;
    for (int i = 0; i < deg; ++i) ssum += sc[i];
    float inv = (deg > 0) ? (1.0f / ssum) : 0.f;

    // value accumulate: thread handles 8 d's (dg) x 2 t's (tq, tq+32)
    int dg = tid & 7;
    int tq = tid >> 3;   // 0..31
    float a0[8], a1[8];
    #pragma unroll
    for (int j = 0; j < 8; ++j) { a0[j] = 0.f; a1[j] = 0.f; }
    for (int i = 0; i < deg; ++i) {
        float al = sc[i] * inv;
        int s = sidx[i];
        int sb = s / CID, scn = s - sb * CID;
        const u16* vx = xb + ((size_t)sb * SEQ + tq) * ICD + scn * DIN + (dg << 3);
        uint4 v0 = *(const uint4*)vx;
        uint4 v1 = *(const uint4*)(vx + (size_t)32 * ICD);
        a0[0] += al * bflo(v0.x); a0[1] += al * bfhi(v0.x);
        a0[2] += al * bflo(v0.y); a0[3] += al * bfhi(v0.y);
        a0[4] += al * bflo(v0.z); a0[5] += al * bfhi(v0.z);
        a0[6] += al * bflo(v0.w); a0[7] += al * bfhi(v0.w);
        a1[0] += al * bflo(v1.x); a1[1] += al * bfhi(v1.x);
        a1[2] += al * bflo(v1.y); a1[3] += al * bfhi(v1.y);
        a1[4] += al * bflo(v1.z); a1[5] += al * bfhi(v1.z);
        a1[6] += al * bflo(v1.w); a1[7] += al * bfhi(v1.w);
    }
    u16* py = yb + ((size_t)b * SEQ + tq) * ICD + c * DIN + (dg << 3);
    uint4 o0, o1;
    o0.x = packbf(a0[0], a0[1]); o0.y = packbf(a0[2], a0[3]);
    o0.z = packbf(a0[4], a0[5]); o0.w = packbf(a0[6], a0[7]);
    o1.x = packbf(a1[0], a1[1]); o1.y = packbf(a1[2], a1[3]);
    o1.z = packbf(a1[4], a1[5]); o1.w = packbf(a1[6], a1[7]);
    *(uint4*)py = o0;
    *(uint4*)(py + (size_t)32 * ICD) = o1;
}

// ---------------- conv weight -> MFMA B-fragment layout (bf16) ----------------
// wf[kstep][w][ntile][lane][j] = cw[oc = ntile*16 + (lane&15)][ic = kstep*32 + 8*(lane>>4) + j][w]
__global__ __launch_bounds__(256) void wprep_kernel(const float* __restrict__ cw,
                                                    u16* __restrict__ wf) {
    __shared__ float s_cw[128][100];  // 96 cols + pad
    int kstep = blockIdx.x;           // 0..415
    int ic0 = kstep * 32;
    int tid = threadIdx.x;
    {
        int oc = tid >> 1, hf = tid & 1;
        const float* src = cw + (size_t)oc * (ICD * KW) + (size_t)ic0 * 3 + hf * 48;
        #pragma unroll
        for (int u = 0; u < 48; ++u) {
            int col = hf * 48 + u;
            int ic = ic0 + col / 3;
            float v = 0.f;
            if (ic < ICD) v = src[u];
            s_cw[oc][col] = v;
        }
    }
    __syncthreads();
    #pragma unroll
    for (int r = 0; r < 6; ++r) {
        int f = tid + 256 * r;        // 0..1535
        int lane = f & 63;
        int nt = (f >> 6) & 7;
        int w = f >> 9;
        int row = nt * 16 + (lane & 15);
        int cb = 8 * (lane >> 4);
        uint4 o;
        u32 p[4];
        #pragma unroll
        for (int pj = 0; pj < 4; ++pj) {
            float v0 = s_cw[row][(cb + 2 * pj) * 3 + w];
            float v1 = s_cw[row][(cb + 2 * pj + 1) * 3 + w];
            p[pj] = packbf(v0, v1);
        }
        o.x = p[0]; o.y = p[1]; o.z = p[2]; o.w = p[3];
        size_t off = (((size_t)(kstep * 3 + w) * 8 + nt) * 64 + lane) * 8;
        *(uint4*)(wf + off) = o;
    }
}

// ---------------- conv1d as MFMA GEMM, split-K ----------------
__global__ __launch_bounds__(256) void conv_kernel(const u16* __restrict__ yb,
                                                   const u16* __restrict__ wf,
                                                   float* __restrict__ partial) {
    int bid = blockIdx.x;
    int b = bid & 15;
    int kc = bid >> 4;                 // 0..31
    int tid = threadIdx.x;
    int lane = tid & 63;
    int wid = tid >> 6;                // wave -> t-tile
    int t0 = wid * 16;
    int lrow = lane & 15;              // A row (t_local), D col (oc_local)
    int lq = lane >> 4;                // k-group / D row group
    f32x4 acc[8];
    #pragma unroll
    for (int n = 0; n < 8; ++n) acc[n] = (f32x4){0.f, 0.f, 0.f, 0.f};

    const u16* ybase = yb + (size_t)b * SEQ * ICD + lq * 8;
    for (int ks = 0; ks < KSPC; ++ks) {
        int kstep = kc * KSPC + ks;
        int ic0 = kstep * 32;
        bf16x8 a[3];
        #pragma unroll
        for (int w = 0; w < 3; ++w) {
            int ts = t0 + lrow + w - 1;
            bf16x8 av = {0, 0, 0, 0, 0, 0, 0, 0};
            if ((unsigned)ts < SEQ)
                av = *(const bf16x8*)(ybase + (size_t)ts * ICD + ic0);
            a[w] = av;
        }
        const u16* wfp = wf + (size_t)kstep * 3 * 8 * 64 * 8 + lane * 8;
        #pragma unroll
        for (int w = 0; w < 3; ++w) {
            #pragma unroll
            for (int n = 0; n < 8; ++n) {
                bf16x8 bv = *(const bf16x8*)(wfp + (size_t)((w * 8 + n) * 64) * 8);
                acc[n] = __builtin_amdgcn_mfma_f32_16x16x32_bf16(a[w], bv, acc[n], 0, 0, 0);
            }
        }
    }
    float* pp = partial + (size_t)kc * (BZ * SEQ * OCN / NKC) * NKC / NKC;  // see below
    pp = partial + (size_t)kc * 131072 + (size_t)b * SEQ * OCN;
    #pragma unroll
    for (int n = 0; n < 8; ++n) {
        #pragma unroll
        for (int r = 0; r < 4; ++r) {
            int t = t0 + lq * 4 + r;
            pp[(size_t)t * OCN + n * 16 + lrow] = acc[n][r];
        }
    }
}

// ---------------- split-K reduce ----------------
__global__ __launch_bounds__(256) void reduce_kernel(const float* __restrict__ partial,
                                                     float* __restrict__ out) {
    int i = blockIdx.x * 256 + threadIdx.x;   // 131072 total
    float s = 0.f;
    #pragma unroll
    for (int kc = 0; kc < NKC; ++kc) s += partial[(size_t)kc * 131072 + i];
    out[i] = s;
}

extern "C" void kernel_launch(void* const* d_in, const int* in_sizes, int n_in,
                              void* d_out, int out_size, void* d_ws, size_t ws_size,
                              hipStream_t stream) {
    const float* x   = (const float*)d_in[0];
    const float* Wq  = (const float*)d_in[1];
    const float* bqv = (const float*)d_in[2];
    const float* Wk  = (const float*)d_in[3];
    const float* bkv = (const float*)d_in[4];
    const float* cw  = (const float*)d_in[5];
    const int* esrc  = (const int*)d_in[6];
    const int* edst  = (const int*)d_in[7];

    char* ws = (char*)d_ws;
    size_t o = 0;
    auto alloc = [&](size_t bytes) {
        void* p = ws + o;
        o += (bytes + 255) & ~(size_t)255;
        return p;
    };
    u16*   xb    = (u16*)alloc(XTOT * 2);                 // 27.1 MB (aliased by partial later)
    u16*   yb    = (u16*)alloc(XTOT * 2);                 // 27.1 MB
    u16*   wf    = (u16*)alloc((size_t)NKPAD * 3 * 8 * 64 * 8 * 2);  // 10.2 MB
    float* meanx = (float*)alloc((size_t)NN * DIN * 4);
    float* q     = (float*)alloc((size_t)NN * OCN * 4);
    float* k     = (float*)alloc((size_t)NN * OCN * 4);
    int*   cnt   = (int*)alloc(4096 * 4);
    int*   fill  = (int*)alloc(4096 * 4);
    int*   offs  = (int*)alloc(4352 * 4);
    int*   csr   = (int*)alloc((size_t)NE * 4);
    float* partial = (float*)xb;   // alias: xb dead after gather, partial live conv->reduce (16.8 MB < 27.1 MB)

    hipMemsetAsync(cnt, 0, 4096 * 4, stream);
    hipMemsetAsync(fill, 0, 4096 * 4, stream);

    cvt_kernel<<<dim3((unsigned)(XTOT / 8 / 256)), dim3(256), 0, stream>>>(x, xb);
    mean_kernel<<<dim3((NN * DIN + 255) / 256), dim3(256), 0, stream>>>(x, meanx);
    qk_kernel<<<dim3(NN / 8), dim3(128), 0, stream>>>(meanx, Wq, bqv, Wk, bkv, q, k);
    hist_kernel<<<dim3((NE + 255) / 256), dim3(256), 0, stream>>>(edst, cnt);
    scan_kernel<<<dim3(1), dim3(1024), 0, stream>>>(cnt, offs);
    scatter_kernel<<<dim3((NE + 255) / 256), dim3(256), 0, stream>>>(esrc, edst, offs, fill, csr);
    wprep_kernel<<<dim3(NKPAD), dim3(256), 0, stream>>>(cw, wf);
    gather_kernel<<<dim3(NN), dim3(256), 0, stream>>>(xb, q, k, offs, csr, yb);
    conv_kernel<<<dim3(16 * NKC), dim3(256), 0, stream>>>(yb, wf, partial);
    reduce_kernel<<<dim3(131072 / 256), dim3(256), 0, stream>>>(partial, (float*)d_out);
}

// Round 3
// 193.143 us; speedup vs baseline: 2.3308x; 1.1453x over previous
//
#include <hip/hip_runtime.h>
#include <hip/hip_bf16.h>
#include <math.h>

#define BZ 16
#define SEQ 64
#define CID 207
#define DIN 64
#define OCN 128
#define NN (BZ*CID)        // 3312
#define NE (NN*16)         // 52992
#define ICD (CID*DIN)      // 13248
#define KW 3
#define NKSTEP 414         // ICD/32
#define NKPAD 416          // padded to 32*13
#define NKC 32             // K-split chunks
#define KSPC 13            // ksteps per chunk
#define XTOT ((size_t)BZ*SEQ*ICD)   // 13565952
#define TCH 8              // t-chunk for gather
#define NCHUNK (SEQ/TCH)   // 8

typedef __attribute__((ext_vector_type(8))) short bf16x8;
typedef __attribute__((ext_vector_type(4))) float f32x4;
typedef unsigned short u16;
typedef unsigned int u32;

__device__ __forceinline__ float bflo(u32 u) {
    u32 v = u << 16;
    return __builtin_bit_cast(float, v);
}
__device__ __forceinline__ float bfhi(u32 u) {
    u32 v = u & 0xFFFF0000u;
    return __builtin_bit_cast(float, v);
}
__device__ __forceinline__ u16 f2bf(float f) {
    __hip_bfloat16 h = __float2bfloat16(f);
    return __builtin_bit_cast(u16, h);
}
__device__ __forceinline__ u32 packbf(float f0, float f1) {
    return ((u32)f2bf(f1) << 16) | (u32)f2bf(f0);
}

// ---------------- fused x->bf16 transpose (xt[t][n][d]) + mean over t ----------------
__global__ __launch_bounds__(256) void cvtmean_kernel(const float* __restrict__ x,
                                                      u16* __restrict__ xt,
                                                      float* __restrict__ meanx) {
    int bb = blockIdx.x;            // batch
    int cg = blockIdx.y;            // c-group of 16
    int tid = threadIdx.x;
    int cl = tid >> 4;              // 0..15
    int dq = (tid & 15) << 2;       // d0 of 4
    int c = cg * 16 + cl;
    if (c >= CID) return;
    int n = bb * CID + c;
    const float* px = x + (size_t)bb * SEQ * ICD + (size_t)c * DIN + dq;
    u16* pxt = xt + (size_t)n * DIN + dq;
    float ax = 0.f, ay = 0.f, az = 0.f, aw = 0.f;
    #pragma unroll 4
    for (int t = 0; t < SEQ; ++t) {
        float4 v = *(const float4*)(px + (size_t)t * ICD);
        ax += v.x; ay += v.y; az += v.z; aw += v.w;
        uint2 w2;
        w2.x = packbf(v.x, v.y);
        w2.y = packbf(v.z, v.w);
        *(uint2*)(pxt + (size_t)t * NN * DIN) = w2;
    }
    const float s = 1.0f / SEQ;
    float4 m4 = make_float4(ax * s, ay * s, az * s, aw * s);
    *(float4*)(meanx + (size_t)n * DIN + dq) = m4;
}

// ---------------- q/k projection ----------------
__global__ __launch_bounds__(128) void qk_kernel(const float* __restrict__ meanx,
                                                 const float* __restrict__ Wq,
                                                 const float* __restrict__ bq,
                                                 const float* __restrict__ Wk,
                                                 const float* __restrict__ bk,
                                                 float* __restrict__ q,
                                                 float* __restrict__ k) {
    __shared__ float ms[8][DIN];
    int n0 = blockIdx.x * 8;
    int tid = threadIdx.x;
    for (int i = tid; i < 8 * DIN; i += 128) {
        int nn = n0 + (i >> 6);
        ms[i >> 6][i & 63] = (nn < NN) ? meanx[(size_t)nn * DIN + (i & 63)] : 0.f;
    }
    __syncthreads();
    int j = tid;
    float accq[8], acck[8];
    float bqv = bq[j], bkv = bk[j];
    #pragma unroll
    for (int r = 0; r < 8; ++r) { accq[r] = bqv; acck[r] = bkv; }
    for (int d = 0; d < DIN; ++d) {
        float wq = Wq[d * OCN + j], wk = Wk[d * OCN + j];
        #pragma unroll
        for (int r = 0; r < 8; ++r) {
            float mv = ms[r][d];
            accq[r] += mv * wq;
            acck[r] += mv * wk;
        }
    }
    const float qscale = 0.088388347648318447f;  // 1/sqrt(128)
    #pragma unroll
    for (int r = 0; r < 8; ++r) {
        int nn = n0 + r;
        if (nn < NN) {
            q[(size_t)nn * OCN + j] = accq[r] * qscale;
            k[(size_t)nn * OCN + j] = acck[r];
        }
    }
}

// ---------------- CSR build ----------------
__global__ __launch_bounds__(256) void hist_kernel(const int* __restrict__ dst,
                                                   int* __restrict__ cnt) {
    int e = blockIdx.x * 256 + threadIdx.x;
    if (e < NE) atomicAdd(&cnt[dst[e]], 1);
}

__global__ __launch_bounds__(1024) void scan_kernel(const int* __restrict__ cnt,
                                                    int* __restrict__ offs) {
    __shared__ int sums[1024], sums2[1024];
    int tid = threadIdx.x;
    int base = tid * 4;
    int v[4];
    #pragma unroll
    for (int i = 0; i < 4; ++i) v[i] = (base + i < NN) ? cnt[base + i] : 0;
    sums[tid] = v[0] + v[1] + v[2] + v[3];
    __syncthreads();
    int* a = sums;
    int* b2 = sums2;
    for (int off = 1; off < 1024; off <<= 1) {
        int val = a[tid] + ((tid >= off) ? a[tid - off] : 0);
        b2[tid] = val;
        __syncthreads();
        int* t = a; a = b2; b2 = t;
    }
    int prev = (tid > 0) ? a[tid - 1] : 0;
    int run = prev;
    #pragma unroll
    for (int i = 0; i < 4; ++i) {
        if (base + i <= NN) offs[base + i] = run;
        run += v[i];
    }
}

__global__ __launch_bounds__(256) void scatter_kernel(const int* __restrict__ src,
                                                      const int* __restrict__ dst,
                                                      const int* __restrict__ offs,
                                                      int* __restrict__ fill,
                                                      int* __restrict__ csr_src) {
    int e = blockIdx.x * 256 + threadIdx.x;
    if (e >= NE) return;
    int d0 = dst[e];
    int pos = offs[d0] + atomicAdd(&fill[d0], 1);
    csr_src[pos] = src[e];
}

// ---------------- per-edge attention weights (scores + segment softmax) ----------------
__global__ __launch_bounds__(256) void alpha_kernel(const float* __restrict__ q,
                                                    const float* __restrict__ k,
                                                    const int* __restrict__ offs,
                                                    const int* __restrict__ csr,
                                                    float* __restrict__ alpha) {
    __shared__ float qs[OCN];
    __shared__ float sc[1024];
    __shared__ int sidx[1024];
    int n = blockIdx.x;
    int start = offs[n];
    int deg = offs[n + 1] - start;
    if (deg > 1024) deg = 1024;
    int tid = threadIdx.x;
    if (tid < OCN) qs[tid] = q[(size_t)n * OCN + tid];
    for (int i = tid; i < deg; i += 256) sidx[i] = csr[start + i];
    __syncthreads();
    int lane = tid & 63;
    int wv = tid >> 6;
    for (int i = wv; i < deg; i += 4) {
        const float* kk = k + (size_t)sidx[i] * OCN;
        float p = kk[lane] * qs[lane] + kk[lane + 64] * qs[lane + 64];
        #pragma unroll
        for (int off = 32; off; off >>= 1) p += __shfl_down(p, off);
        if (lane == 0) sc[i] = p;
    }
    __syncthreads();
    float m = -1e30f;
    for (int i = 0; i < deg; ++i) m = fmaxf(m, sc[i]);
    __syncthreads();
    for (int i = tid; i < deg; i += 256) sc[i] = __expf(sc[i] - m);
    __syncthreads();
    float ssum = 0.f;
    for (int i = 0; i < deg; ++i) ssum += sc[i];
    float inv = (deg > 0) ? (1.0f / ssum) : 0.f;
    for (int i = tid; i < deg; i += 256) alpha[start + i] = sc[i] * inv;
}

// ---------------- t-chunked weighted gather: out[n, t0:t0+8, :] = sum_e alpha_e xt[t][src][:] ----------------
__global__ __launch_bounds__(256) void gather2_kernel(const u16* __restrict__ xt,
                                                      const float* __restrict__ alpha,
                                                      const int* __restrict__ offs,
                                                      const int* __restrict__ csr,
                                                      u16* __restrict__ yb) {
    __shared__ int sidx[1024];
    __shared__ float sal[1024];
    __shared__ float sacc[4][TCH * DIN];
    int n = blockIdx.x;
    int t0 = blockIdx.y * TCH;
    int b = n / CID, c = n - b * CID;
    int start = offs[n];
    int deg = offs[n + 1] - start;
    if (deg > 1024) deg = 1024;
    int tid = threadIdx.x;
    for (int i = tid; i < deg; i += 256) {
        sidx[i] = csr[start + i];
        sal[i] = alpha[start + i];
    }
    __syncthreads();
    int ew = tid >> 6;          // edge-worker wave 0..3
    int lane = tid & 63;
    int t = lane >> 3;          // 0..7
    int dg = lane & 7;          // 8 d's each (16B)
    float acc[8];
    #pragma unroll
    for (int j = 0; j < 8; ++j) acc[j] = 0.f;
    const u16* xbase = xt + ((size_t)(t0 + t) * NN) * DIN + (dg << 3);
    for (int i = ew; i < deg; i += 4) {
        int s = sidx[i];
        float a = sal[i];
        uint4 v = *(const uint4*)(xbase + (size_t)s * DIN);
        acc[0] += a * bflo(v.x); acc[1] += a * bfhi(v.x);
        acc[2] += a * bflo(v.y); acc[3] += a * bfhi(v.y);
        acc[4] += a * bflo(v.z); acc[5] += a * bfhi(v.z);
        acc[6] += a * bflo(v.w); acc[7] += a * bfhi(v.w);
    }
    int base = t * DIN + (dg << 3);
    #pragma unroll
    for (int j = 0; j < 8; ++j) sacc[ew][base + j] = acc[j];
    __syncthreads();
    int e = tid * 2;
    int tt = e >> 6, d = e & 63;
    float v0 = sacc[0][e] + sacc[1][e] + sacc[2][e] + sacc[3][e];
    float v1 = sacc[0][e + 1] + sacc[1][e + 1] + sacc[2][e + 1] + sacc[3][e + 1];
    u32 pw = packbf(v0, v1);
    *(u32*)(yb + ((size_t)b * SEQ + t0 + tt) * ICD + c * DIN + d) = pw;
}

// ---------------- conv weight -> MFMA B-fragment layout (bf16) ----------------
__global__ __launch_bounds__(256) void wprep_kernel(const float* __restrict__ cw,
                                                    u16* __restrict__ wf) {
    __shared__ float s_cw[128][100];  // 96 cols + pad
    int kstep = blockIdx.x;           // 0..415
    int ic0 = kstep * 32;
    int tid = threadIdx.x;
    {
        int oc = tid >> 1, hf = tid & 1;
        const float* src = cw + (size_t)oc * (ICD * KW) + (size_t)ic0 * 3 + hf * 48;
        #pragma unroll
        for (int u = 0; u < 48; ++u) {
            int col = hf * 48 + u;
            int ic = ic0 + col / 3;
            float v = 0.f;
            if (ic < ICD) v = src[u];
            s_cw[oc][col] = v;
        }
    }
    __syncthreads();
    #pragma unroll
    for (int r = 0; r < 6; ++r) {
        int f = tid + 256 * r;        // 0..1535
        int lane = f & 63;
        int nt = (f >> 6) & 7;
        int w = f >> 9;
        int row = nt * 16 + (lane & 15);
        int cb = 8 * (lane >> 4);
        uint4 o;
        u32 p[4];
        #pragma unroll
        for (int pj = 0; pj < 4; ++pj) {
            float v0 = s_cw[row][(cb + 2 * pj) * 3 + w];
            float v1 = s_cw[row][(cb + 2 * pj + 1) * 3 + w];
            p[pj] = packbf(v0, v1);
        }
        o.x = p[0]; o.y = p[1]; o.z = p[2]; o.w = p[3];
        size_t off = (((size_t)(kstep * 3 + w) * 8 + nt) * 64 + lane) * 8;
        *(uint4*)(wf + off) = o;
    }
}

// ---------------- conv1d as MFMA GEMM, split-K ----------------
__global__ __launch_bounds__(256) void conv_kernel(const u16* __restrict__ yb,
                                                   const u16* __restrict__ wf,
                                                   float* __restrict__ partial) {
    int bid = blockIdx.x;
    int b = bid & 15;
    int kc = bid >> 4;                 // 0..31
    int tid = threadIdx.x;
    int lane = tid & 63;
    int wid = tid >> 6;                // wave -> t-tile
    int t0 = wid * 16;
    int lrow = lane & 15;              // A row (t_local), D col (oc_local)
    int lq = lane >> 4;                // k-group / D row group
    f32x4 acc[8];
    #pragma unroll
    for (int n = 0; n < 8; ++n) acc[n] = (f32x4){0.f, 0.f, 0.f, 0.f};

    const u16* ybase = yb + (size_t)b * SEQ * ICD + lq * 8;
    for (int ks = 0; ks < KSPC; ++ks) {
        int kstep = kc * KSPC + ks;
        int ic0 = kstep * 32;
        bf16x8 a[3];
        #pragma unroll
        for (int w = 0; w < 3; ++w) {
            int ts = t0 + lrow + w - 1;
            bf16x8 av = {0, 0, 0, 0, 0, 0, 0, 0};
            if ((unsigned)ts < SEQ)
                av = *(const bf16x8*)(ybase + (size_t)ts * ICD + ic0);
            a[w] = av;
        }
        const u16* wfp = wf + (size_t)kstep * 3 * 8 * 64 * 8 + lane * 8;
        #pragma unroll
        for (int w = 0; w < 3; ++w) {
            #pragma unroll
            for (int n = 0; n < 8; ++n) {
                bf16x8 bv = *(const bf16x8*)(wfp + (size_t)((w * 8 + n) * 64) * 8);
                acc[n] = __builtin_amdgcn_mfma_f32_16x16x32_bf16(a[w], bv, acc[n], 0, 0, 0);
            }
        }
    }
    float* pp = partial + (size_t)kc * 131072 + (size_t)b * SEQ * OCN;
    #pragma unroll
    for (int n = 0; n < 8; ++n) {
        #pragma unroll
        for (int r = 0; r < 4; ++r) {
            int t = t0 + lq * 4 + r;
            pp[(size_t)t * OCN + n * 16 + lrow] = acc[n][r];
        }
    }
}

// ---------------- split-K reduce ----------------
__global__ __launch_bounds__(256) void reduce_kernel(const float* __restrict__ partial,
                                                     float* __restrict__ out) {
    int i = blockIdx.x * 256 + threadIdx.x;   // 131072 total
    float s = 0.f;
    #pragma unroll
    for (int kc = 0; kc < NKC; ++kc) s += partial[(size_t)kc * 131072 + i];
    out[i] = s;
}

extern "C" void kernel_launch(void* const* d_in, const int* in_sizes, int n_in,
                              void* d_out, int out_size, void* d_ws, size_t ws_size,
                              hipStream_t stream) {
    const float* x   = (const float*)d_in[0];
    const float* Wq  = (const float*)d_in[1];
    const float* bqv = (const float*)d_in[2];
    const float* Wk  = (const float*)d_in[3];
    const float* bkv = (const float*)d_in[4];
    const float* cw  = (const float*)d_in[5];
    const int* esrc  = (const int*)d_in[6];
    const int* edst  = (const int*)d_in[7];

    char* ws = (char*)d_ws;
    size_t o = 0;
    auto alloc = [&](size_t bytes) {
        void* p = ws + o;
        o += (bytes + 255) & ~(size_t)255;
        return p;
    };
    u16*   xt    = (u16*)alloc(XTOT * 2);                 // 27.1 MB (aliased by partial after gather2)
    u16*   yb    = (u16*)alloc(XTOT * 2);                 // 27.1 MB
    u16*   wf    = (u16*)alloc((size_t)NKPAD * 3 * 8 * 64 * 8 * 2);  // 10.2 MB
    float* meanx = (float*)alloc((size_t)NN * DIN * 4);
    float* q     = (float*)alloc((size_t)NN * OCN * 4);
    float* k     = (float*)alloc((size_t)NN * OCN * 4);
    int*   cnt   = (int*)alloc(4096 * 4);
    int*   fill  = (int*)alloc(4096 * 4);
    int*   offs  = (int*)alloc(4352 * 4);
    int*   csr   = (int*)alloc((size_t)NE * 4);
    float* alpha = (float*)alloc((size_t)NE * 4);
    float* partial = (float*)xt;   // alias: xt dead after gather2; partial live conv->reduce (16.8 MB < 27.1 MB)

    hipMemsetAsync(cnt, 0, 4096 * 4, stream);
    hipMemsetAsync(fill, 0, 4096 * 4, stream);

    cvtmean_kernel<<<dim3(16, 13), dim3(256), 0, stream>>>(x, xt, meanx);
    qk_kernel<<<dim3(NN / 8), dim3(128), 0, stream>>>(meanx, Wq, bqv, Wk, bkv, q, k);
    hist_kernel<<<dim3((NE + 255) / 256), dim3(256), 0, stream>>>(edst, cnt);
    scan_kernel<<<dim3(1), dim3(1024), 0, stream>>>(cnt, offs);
    scatter_kernel<<<dim3((NE + 255) / 256), dim3(256), 0, stream>>>(esrc, edst, offs, fill, csr);
    wprep_kernel<<<dim3(NKPAD), dim3(256), 0, stream>>>(cw, wf);
    alpha_kernel<<<dim3(NN), dim3(256), 0, stream>>>(q, k, offs, csr, alpha);
    gather2_kernel<<<dim3(NN, NCHUNK), dim3(256), 0, stream>>>(xt, alpha, offs, csr, yb);
    conv_kernel<<<dim3(16 * NKC), dim3(256), 0, stream>>>(yb, wf, partial);
    reduce_kernel<<<dim3(131072 / 256), dim3(256), 0, stream>>>(partial, (float*)d_out);
}

// Round 4
// 183.556 us; speedup vs baseline: 2.4526x; 1.0522x over previous
//
#include <hip/hip_runtime.h>
#include <hip/hip_bf16.h>
#include <math.h>

#define BZ 16
#define SEQ 64
#define CID 207
#define DIN 64
#define OCN 128
#define NN (BZ*CID)        // 3312
#define NE (NN*16)         // 52992
#define ICD (CID*DIN)      // 13248
#define KW 3
#define NKSTEP 414         // ICD/32
#define NKPAD 416          // padded to 32*13
#define NKC 32             // K-split chunks
#define KSPC 13            // ksteps per chunk
#define XTOT ((size_t)BZ*SEQ*ICD)   // 13565952
#define TCH 8              // t-chunk for gather
#define NCHUNK (SEQ/TCH)   // 8
#define GDEG 256           // max in-degree (actual max ~40 for this data)

typedef __attribute__((ext_vector_type(8))) short bf16x8;
typedef __attribute__((ext_vector_type(4))) float f32x4;
typedef unsigned short u16;
typedef unsigned int u32;

__device__ __forceinline__ float bflo(u32 u) {
    u32 v = u << 16;
    return __builtin_bit_cast(float, v);
}
__device__ __forceinline__ float bfhi(u32 u) {
    u32 v = u & 0xFFFF0000u;
    return __builtin_bit_cast(float, v);
}
__device__ __forceinline__ u16 f2bf(float f) {
    __hip_bfloat16 h = __float2bfloat16(f);
    return __builtin_bit_cast(u16, h);
}
__device__ __forceinline__ u32 packbf(float f0, float f1) {
    return ((u32)f2bf(f1) << 16) | (u32)f2bf(f0);
}

// ---------------- fused x->bf16 transpose (xt[t][n][d]) + mean over t ----------------
__global__ __launch_bounds__(256) void cvtmean_kernel(const float* __restrict__ x,
                                                      u16* __restrict__ xt,
                                                      float* __restrict__ meanx) {
    int bb = blockIdx.x;            // batch
    int cg = blockIdx.y;            // c-group of 16
    int tid = threadIdx.x;
    int cl = tid >> 4;              // 0..15
    int dq = (tid & 15) << 2;       // d0 of 4
    int c = cg * 16 + cl;
    if (c >= CID) return;
    int n = bb * CID + c;
    const float* px = x + (size_t)bb * SEQ * ICD + (size_t)c * DIN + dq;
    u16* pxt = xt + (size_t)n * DIN + dq;
    float ax = 0.f, ay = 0.f, az = 0.f, aw = 0.f;
    #pragma unroll 4
    for (int t = 0; t < SEQ; ++t) {
        float4 v = *(const float4*)(px + (size_t)t * ICD);
        ax += v.x; ay += v.y; az += v.z; aw += v.w;
        uint2 w2;
        w2.x = packbf(v.x, v.y);
        w2.y = packbf(v.z, v.w);
        *(uint2*)(pxt + (size_t)t * NN * DIN) = w2;
    }
    const float s = 1.0f / SEQ;
    float4 m4 = make_float4(ax * s, ay * s, az * s, aw * s);
    *(float4*)(meanx + (size_t)n * DIN + dq) = m4;
}

// ---------------- q/k projection ----------------
__global__ __launch_bounds__(128) void qk_kernel(const float* __restrict__ meanx,
                                                 const float* __restrict__ Wq,
                                                 const float* __restrict__ bq,
                                                 const float* __restrict__ Wk,
                                                 const float* __restrict__ bk,
                                                 float* __restrict__ q,
                                                 float* __restrict__ k) {
    __shared__ float ms[8][DIN];
    int n0 = blockIdx.x * 8;
    int tid = threadIdx.x;
    for (int i = tid; i < 8 * DIN; i += 128) {
        int nn = n0 + (i >> 6);
        ms[i >> 6][i & 63] = (nn < NN) ? meanx[(size_t)nn * DIN + (i & 63)] : 0.f;
    }
    __syncthreads();
    int j = tid;
    float accq[8], acck[8];
    float bqv = bq[j], bkv = bk[j];
    #pragma unroll
    for (int r = 0; r < 8; ++r) { accq[r] = bqv; acck[r] = bkv; }
    for (int d = 0; d < DIN; ++d) {
        float wq = Wq[d * OCN + j], wk = Wk[d * OCN + j];
        #pragma unroll
        for (int r = 0; r < 8; ++r) {
            float mv = ms[r][d];
            accq[r] += mv * wq;
            acck[r] += mv * wk;
        }
    }
    const float qscale = 0.088388347648318447f;  // 1/sqrt(128)
    #pragma unroll
    for (int r = 0; r < 8; ++r) {
        int nn = n0 + r;
        if (nn < NN) {
            q[(size_t)nn * OCN + j] = accq[r] * qscale;
            k[(size_t)nn * OCN + j] = acck[r];
        }
    }
}

// ---------------- CSR build ----------------
__global__ __launch_bounds__(256) void hist_kernel(const int* __restrict__ dst,
                                                   int* __restrict__ cnt) {
    int e = blockIdx.x * 256 + threadIdx.x;
    if (e < NE) atomicAdd(&cnt[dst[e]], 1);
}

__global__ __launch_bounds__(1024) void scan_kernel(const int* __restrict__ cnt,
                                                    int* __restrict__ offs) {
    __shared__ int sums[1024], sums2[1024];
    int tid = threadIdx.x;
    int base = tid * 4;
    int v[4];
    #pragma unroll
    for (int i = 0; i < 4; ++i) v[i] = (base + i < NN) ? cnt[base + i] : 0;
    sums[tid] = v[0] + v[1] + v[2] + v[3];
    __syncthreads();
    int* a = sums;
    int* b2 = sums2;
    for (int off = 1; off < 1024; off <<= 1) {
        int val = a[tid] + ((tid >= off) ? a[tid - off] : 0);
        b2[tid] = val;
        __syncthreads();
        int* t = a; a = b2; b2 = t;
    }
    int prev = (tid > 0) ? a[tid - 1] : 0;
    int run = prev;
    #pragma unroll
    for (int i = 0; i < 4; ++i) {
        if (base + i <= NN) offs[base + i] = run;
        run += v[i];
    }
}

__global__ __launch_bounds__(256) void scatter_kernel(const int* __restrict__ src,
                                                      const int* __restrict__ dst,
                                                      const int* __restrict__ offs,
                                                      int* __restrict__ fill,
                                                      int* __restrict__ csr_src) {
    int e = blockIdx.x * 256 + threadIdx.x;
    if (e >= NE) return;
    int d0 = dst[e];
    int pos = offs[d0] + atomicAdd(&fill[d0], 1);
    csr_src[pos] = src[e];
}

// ---------------- per-edge attention weights (scores + segment softmax) ----------------
__global__ __launch_bounds__(256) void alpha_kernel(const float* __restrict__ q,
                                                    const float* __restrict__ k,
                                                    const int* __restrict__ offs,
                                                    const int* __restrict__ csr,
                                                    float* __restrict__ alpha) {
    __shared__ float qs[OCN];
    __shared__ float sc[GDEG];
    __shared__ int sidx[GDEG];
    int n = blockIdx.x;
    int start = offs[n];
    int deg = offs[n + 1] - start;
    if (deg > GDEG) deg = GDEG;
    int tid = threadIdx.x;
    if (tid < OCN) qs[tid] = q[(size_t)n * OCN + tid];
    for (int i = tid; i < deg; i += 256) sidx[i] = csr[start + i];
    __syncthreads();
    int lane = tid & 63;
    int wv = tid >> 6;
    for (int i = wv; i < deg; i += 4) {
        const float* kk = k + (size_t)sidx[i] * OCN;
        float p = kk[lane] * qs[lane] + kk[lane + 64] * qs[lane + 64];
        #pragma unroll
        for (int off = 32; off; off >>= 1) p += __shfl_down(p, off);
        if (lane == 0) sc[i] = p;
    }
    __syncthreads();
    float m = -1e30f;
    for (int i = 0; i < deg; ++i) m = fmaxf(m, sc[i]);
    __syncthreads();
    for (int i = tid; i < deg; i += 256) sc[i] = __expf(sc[i] - m);
    __syncthreads();
    float ssum = 0.f;
    for (int i = 0; i < deg; ++i) ssum += sc[i];
    float inv = (deg > 0) ? (1.0f / ssum) : 0.f;
    for (int i = tid; i < deg; i += 256) alpha[start + i] = sc[i] * inv;
}

// ---------------- t-chunked weighted gather, XCD-pinned chunks ----------------
// bid = chunk + 8*n : chunk j runs on XCD j (round-robin dispatch), so each
// XCD's 3.4 MB xt[t-slice] stays L2-resident.
__global__ __launch_bounds__(256) void gather2_kernel(const u16* __restrict__ xt,
                                                      const float* __restrict__ alpha,
                                                      const int* __restrict__ offs,
                                                      const int* __restrict__ csr,
                                                      u16* __restrict__ yb) {
    __shared__ int sidx[GDEG];
    __shared__ float sal[GDEG];
    __shared__ float sacc[4][TCH * DIN];
    int bid = blockIdx.x;
    int ch = bid & 7;
    int n = bid >> 3;
    int t0 = ch * TCH;
    int b = n / CID, c = n - b * CID;
    int start = offs[n];
    int deg = offs[n + 1] - start;
    if (deg > GDEG) deg = GDEG;
    int tid = threadIdx.x;
    for (int i = tid; i < deg; i += 256) {
        sidx[i] = csr[start + i] << 6;   // element offset s*DIN
        sal[i] = alpha[start + i];
    }
    __syncthreads();
    int ew = tid >> 6;          // edge-worker wave 0..3
    int lane = tid & 63;
    int t = lane >> 3;          // 0..7
    int dg = lane & 7;          // 8 d's each (16B)
    float acc[8];
    #pragma unroll
    for (int j = 0; j < 8; ++j) acc[j] = 0.f;
    const u16* xbase = xt + ((size_t)(t0 + t) * NN) * DIN + (dg << 3);
    for (int i = ew; i < deg; i += 4) {
        int so = sidx[i];
        float a = sal[i];
        uint4 v = *(const uint4*)(xbase + so);
        acc[0] += a * bflo(v.x); acc[1] += a * bfhi(v.x);
        acc[2] += a * bflo(v.y); acc[3] += a * bfhi(v.y);
        acc[4] += a * bflo(v.z); acc[5] += a * bfhi(v.z);
        acc[6] += a * bflo(v.w); acc[7] += a * bfhi(v.w);
    }
    int base = t * DIN + (dg << 3);
    #pragma unroll
    for (int j = 0; j < 8; ++j) sacc[ew][base + j] = acc[j];
    __syncthreads();
    int e = tid * 2;
    int tt = e >> 6, d = e & 63;
    float v0 = sacc[0][e] + sacc[1][e] + sacc[2][e] + sacc[3][e];
    float v1 = sacc[0][e + 1] + sacc[1][e + 1] + sacc[2][e + 1] + sacc[3][e + 1];
    u32 pw = packbf(v0, v1);
    *(u32*)(yb + ((size_t)b * SEQ + t0 + tt) * ICD + c * DIN + d) = pw;
}

// ---------------- conv weight -> MFMA B-fragment layout (bf16) ----------------
__global__ __launch_bounds__(256) void wprep_kernel(const float* __restrict__ cw,
                                                    u16* __restrict__ wf) {
    __shared__ float s_cw[128][100];  // 96 cols + pad
    int kstep = blockIdx.x;           // 0..415
    int ic0 = kstep * 32;
    int tid = threadIdx.x;
    {
        int oc = tid >> 1, hf = tid & 1;
        const float* src = cw + (size_t)oc * (ICD * KW) + (size_t)ic0 * 3 + hf * 48;
        #pragma unroll
        for (int u = 0; u < 48; ++u) {
            int col = hf * 48 + u;
            int ic = ic0 + col / 3;
            float v = 0.f;
            if (ic < ICD) v = src[u];
            s_cw[oc][col] = v;
        }
    }
    __syncthreads();
    #pragma unroll
    for (int r = 0; r < 6; ++r) {
        int f = tid + 256 * r;        // 0..1535
        int lane = f & 63;
        int nt = (f >> 6) & 7;
        int w = f >> 9;
        int row = nt * 16 + (lane & 15);
        int cb = 8 * (lane >> 4);
        uint4 o;
        u32 p[4];
        #pragma unroll
        for (int pj = 0; pj < 4; ++pj) {
            float v0 = s_cw[row][(cb + 2 * pj) * 3 + w];
            float v1 = s_cw[row][(cb + 2 * pj + 1) * 3 + w];
            p[pj] = packbf(v0, v1);
        }
        o.x = p[0]; o.y = p[1]; o.z = p[2]; o.w = p[3];
        size_t off = (((size_t)(kstep * 3 + w) * 8 + nt) * 64 + lane) * 8;
        *(uint4*)(wf + off) = o;
    }
}

// ---------------- conv1d as MFMA GEMM, split-K + split-N ----------------
// bid = b + 16*kc + 512*nh ; each block: 64 t x 64 oc x (13 ksteps * 32 ic)
__global__ __launch_bounds__(256) void conv_kernel(const u16* __restrict__ yb,
                                                   const u16* __restrict__ wf,
                                                   float* __restrict__ partial) {
    int bid = blockIdx.x;
    int b = bid & 15;
    int kc = (bid >> 4) & 31;          // 0..31
    int nh = bid >> 9;                 // 0..1 (oc half)
    int tid = threadIdx.x;
    int lane = tid & 63;
    int wid = tid >> 6;                // wave -> t-tile
    int t0 = wid * 16;
    int lrow = lane & 15;              // A row (t_local), D col (oc_local)
    int lq = lane >> 4;                // k-group / D row group
    f32x4 acc[4];
    #pragma unroll
    for (int n = 0; n < 4; ++n) acc[n] = (f32x4){0.f, 0.f, 0.f, 0.f};

    const u16* ybase = yb + (size_t)b * SEQ * ICD + lq * 8;
    for (int ks = 0; ks < KSPC; ++ks) {
        int kstep = kc * KSPC + ks;
        int ic0 = kstep * 32;
        bf16x8 a[3];
        #pragma unroll
        for (int w = 0; w < 3; ++w) {
            int ts = t0 + lrow + w - 1;
            bf16x8 av = {0, 0, 0, 0, 0, 0, 0, 0};
            if ((unsigned)ts < SEQ)
                av = *(const bf16x8*)(ybase + (size_t)ts * ICD + ic0);
            a[w] = av;
        }
        const u16* wfp = wf + (size_t)kstep * 3 * 8 * 64 * 8 + lane * 8;
        #pragma unroll
        for (int w = 0; w < 3; ++w) {
            #pragma unroll
            for (int n = 0; n < 4; ++n) {
                bf16x8 bv = *(const bf16x8*)(wfp + (size_t)((w * 8 + nh * 4 + n) * 64) * 8);
                acc[n] = __builtin_amdgcn_mfma_f32_16x16x32_bf16(a[w], bv, acc[n], 0, 0, 0);
            }
        }
    }
    float* pp = partial + (size_t)kc * 131072 + (size_t)b * SEQ * OCN;
    #pragma unroll
    for (int n = 0; n < 4; ++n) {
        #pragma unroll
        for (int r = 0; r < 4; ++r) {
            int t = t0 + lq * 4 + r;
            pp[(size_t)t * OCN + (nh * 4 + n) * 16 + lrow] = acc[n][r];
        }
    }
}

// ---------------- split-K reduce ----------------
__global__ __launch_bounds__(256) void reduce_kernel(const float* __restrict__ partial,
                                                     float* __restrict__ out) {
    int i = blockIdx.x * 256 + threadIdx.x;   // 131072 total
    float s = 0.f;
    #pragma unroll
    for (int kc = 0; kc < NKC; ++kc) s += partial[(size_t)kc * 131072 + i];
    out[i] = s;
}

extern "C" void kernel_launch(void* const* d_in, const int* in_sizes, int n_in,
                              void* d_out, int out_size, void* d_ws, size_t ws_size,
                              hipStream_t stream) {
    const float* x   = (const float*)d_in[0];
    const float* Wq  = (const float*)d_in[1];
    const float* bqv = (const float*)d_in[2];
    const float* Wk  = (const float*)d_in[3];
    const float* bkv = (const float*)d_in[4];
    const float* cw  = (const float*)d_in[5];
    const int* esrc  = (const int*)d_in[6];
    const int* edst  = (const int*)d_in[7];

    char* ws = (char*)d_ws;
    size_t o = 0;
    auto alloc = [&](size_t bytes) {
        void* p = ws + o;
        o += (bytes + 255) & ~(size_t)255;
        return p;
    };
    u16*   xt    = (u16*)alloc(XTOT * 2);                 // 27.1 MB (aliased by partial after gather2)
    u16*   yb    = (u16*)alloc(XTOT * 2);                 // 27.1 MB
    u16*   wf    = (u16*)alloc((size_t)NKPAD * 3 * 8 * 64 * 8 * 2);  // 10.2 MB
    float* meanx = (float*)alloc((size_t)NN * DIN * 4);
    float* q     = (float*)alloc((size_t)NN * OCN * 4);
    float* k     = (float*)alloc((size_t)NN * OCN * 4);
    int*   cnt   = (int*)alloc(4096 * 4);
    int*   fill  = (int*)alloc(4096 * 4);
    int*   offs  = (int*)alloc(4352 * 4);
    int*   csr   = (int*)alloc((size_t)NE * 4);
    float* alpha = (float*)alloc((size_t)NE * 4);
    float* partial = (float*)xt;   // alias: xt dead after gather2; partial live conv->reduce (16.8 MB < 27.1 MB)

    hipMemsetAsync(cnt, 0, 4096 * 4, stream);
    hipMemsetAsync(fill, 0, 4096 * 4, stream);

    cvtmean_kernel<<<dim3(16, 13), dim3(256), 0, stream>>>(x, xt, meanx);
    qk_kernel<<<dim3(NN / 8), dim3(128), 0, stream>>>(meanx, Wq, bqv, Wk, bkv, q, k);
    hist_kernel<<<dim3((NE + 255) / 256), dim3(256), 0, stream>>>(edst, cnt);
    scan_kernel<<<dim3(1), dim3(1024), 0, stream>>>(cnt, offs);
    scatter_kernel<<<dim3((NE + 255) / 256), dim3(256), 0, stream>>>(esrc, edst, offs, fill, csr);
    wprep_kernel<<<dim3(NKPAD), dim3(256), 0, stream>>>(cw, wf);
    alpha_kernel<<<dim3(NN), dim3(256), 0, stream>>>(q, k, offs, csr, alpha);
    gather2_kernel<<<dim3(NN * NCHUNK), dim3(256), 0, stream>>>(xt, alpha, offs, csr, yb);
    conv_kernel<<<dim3(16 * NKC * 2), dim3(256), 0, stream>>>(yb, wf, partial);
    reduce_kernel<<<dim3(131072 / 256), dim3(256), 0, stream>>>(partial, (float*)d_out);
}